// Round 22
// baseline (168.192 us; speedup 1.0000x reference)
//
#include <hip/hip_runtime.h>
#include <hip/hip_cooperative_groups.h>
#include <math.h>
#include <float.h>
#include <limits.h>

namespace cg = cooperative_groups;

#define NBATCH 4
#define NPROP  4096
#define NCLS   91
#define NFG    90
#define NDET   100
#define CCAP   1024            // per-(image,class) bucket cap (measured n ~ 80-350)
#define BN     (NBATCH * NPROP)
#define SLOTS  (NFG * NDET)    // 9000 survivor slots per image
#define CHUNK  128             // NMS matrix-walk chunk size
#define CPAD   32              // counter padding: 32 ints = 128 B per bucket counter
#define GRID   256
#define TPB    1024

typedef unsigned long long ull;

static __device__ __forceinline__ float clampf(float x, float lo, float hi) {
    return fminf(fmaxf(x, lo), hi);
}

// Decode + clip one (proposal, class) box. Identical arithmetic everywhere it is
// used -> bitwise-identical results (validated absmax 0.0, R1-R21).
static __device__ __forceinline__ void decode_box(int b, int np, int c,
    const float* __restrict__ props, const float* __restrict__ deltas,
    float W, float H, float& bx1, float& by1, float& bx2, float& by2)
{
    const float* pr = props + ((size_t)b * NPROP + np) * 4;
    const float x1 = pr[0], y1 = pr[1], x2 = pr[2], y2 = pr[3];
    const float w = x2 - x1, h = y2 - y1;
    const float cx = x1 + 0.5f * w, cy = y1 + 0.5f * h;
    const float* d = deltas + (((size_t)b * NPROP + np) * NCLS + c) * 4;
    const float BBC = 4.135166556742356f;   // log(1000/16)
    const float dx = d[0] / 10.0f;
    const float dy = d[1] / 10.0f;
    const float dw = fminf(d[2] / 5.0f, BBC);
    const float dh = fminf(d[3] / 5.0f, BBC);
    const float pcx = dx * w + cx;
    const float pcy = dy * h + cy;
    const float pw = expf(dw) * w;
    const float ph = expf(dh) * h;
    bx1 = clampf(pcx - 0.5f * pw, 0.0f, W);
    by1 = clampf(pcy - 0.5f * ph, 0.0f, H);
    bx2 = clampf(pcx + 0.5f * pw, 0.0f, W);
    by2 = clampf(pcy + 0.5f * ph, 0.0f, H);
}

// IoU > 0.5 predicate, identical float expression to all validated rounds.
static __device__ __forceinline__ bool iou_gt(const float4 S, const float4 Q, float aq)
{
    const float iw = fmaxf(fminf(S.z, Q.z) - fmaxf(S.x, Q.x), 0.0f);
    const float ih = fmaxf(fminf(S.w, Q.w) - fmaxf(S.y, Q.y), 0.0f);
    const float inter = iw * ih;
    const float as = (S.z - S.x) * (S.w - S.y);
    return inter / (as + aq - inter) > 0.5f;
}

// Block-wide exclusive scan over 1024 threads (wave shfl scan + 16 wave totals).
static __device__ __forceinline__ int block_excl_scan(int v, int t, int* wtot)
{
    const int lane = t & 63, wid = t >> 6;
    int inc = v;
    #pragma unroll
    for (int s = 1; s < 64; s <<= 1) {
        const int u = __shfl_up(inc, s);
        if (lane >= s) inc += u;
    }
    if (lane == 63) wtot[wid] = inc;
    __syncthreads();
    int base = 0;
    for (int w2 = 0; w2 < wid; ++w2) base += wtot[w2];
    __syncthreads();                 // protect wtot for the next call
    return base + inc - v;
}

// Single cooperative kernel: zero -> decode -> per-class NMS -> select,
// separated by grid-wide syncs. All compute bodies carry the validated
// (absmax 0.0) arithmetic; only thread-mapping strides differ.
__global__ __launch_bounds__(TPB, 4) void mega_kernel(
    const float* __restrict__ logits, const float* __restrict__ props,
    const float* __restrict__ deltas, const int* __restrict__ imgsh,
    int* __restrict__ cntPad, ull* __restrict__ cKeys, float4* __restrict__ cBox,
    ull* __restrict__ svKeys, float* __restrict__ out)
{
    cg::grid_group grid = cg::this_grid();
    const int t    = threadIdx.x;
    const int lane = t & 63;
    const int wid  = t >> 6;

    __shared__ __align__(16) ull smem[4608];       // 36.9 KB, carved per phase
    __shared__ int s_ns, s_T, s_above, s_total, wtot[16];
    __shared__ ull s_best;

    // ---------------- Phase 0: zero padded bucket counters ----------------
    for (int i = blockIdx.x * TPB + t; i < NBATCH * NFG * CPAD; i += GRID * TPB)
        cntPad[i] = 0;
    grid.sync();

    // ---------------- Phase 1: fused decode (wave per proposal) ----------------
    for (int p = blockIdx.x * 16 + wid; p < BN; p += GRID * 16) {
        const int b = p >> 12;
        const int np = p & (NPROP - 1);
        const float* lrow = logits + (size_t)p * NCLS;

        const float a  = lrow[lane];
        const float a2 = (lane + 64 < NCLS) ? lrow[lane + 64] : -INFINITY;

        float m = fmaxf(a, a2);                    // level s=64
        #pragma unroll
        for (int s = 32; s > 0; s >>= 1) m = fmaxf(m, __shfl_down(m, s));
        m = __shfl(m, 0);

        const float e0 = expf(a - m);
        const float e1 = (lane + 64 < NCLS) ? expf(a2 - m) : 0.0f;
        float sum = e0 + e1;                       // level s=64
        #pragma unroll
        for (int s = 32; s > 0; s >>= 1) sum += __shfl_down(sum, s);
        sum = __shfl(sum, 0);

        const float W = (float)imgsh[b * 2 + 1];
        const float H = (float)imgsh[b * 2 + 0];

        #pragma unroll
        for (int half = 0; half < 2; ++half) {
            const int c = lane + half * 64;        // class index
            if (c < 1 || c >= NCLS) continue;
            const float e = half ? e1 : e0;
            const float score = e / sum;           // bitwise = validated expr
            if (!(score > 0.05f)) continue;
            float bx1, by1, bx2, by2;
            decode_box(b, np, c, props, deltas, W, H, bx1, by1, bx2, by2);
            if (!((bx2 - bx1) >= 0.01f && (by2 - by1) >= 0.01f)) continue;
            const int cm1 = c - 1;
            const unsigned flat = (unsigned)(np * NFG + cm1);
            const ull key = ((ull)__float_as_uint(score) << 32) | (unsigned)(~flat);
            const int bucket = b * NFG + cm1;
            const int pos = atomicAdd(&cntPad[bucket * CPAD], 1);  // own 128B line
            if (pos < CCAP) {
                cKeys[(size_t)bucket * CCAP + pos] = key;
                cBox[(size_t)bucket * CCAP + pos]  = make_float4(bx1, by1, bx2, by2);
            }
        }
    }
    grid.sync();

    // ---------------- Phase 2: per-class NMS (360 tasks, grid-strided) --------
    {
        ull* sk        = smem;                     // [0,1024)
        ull* sks       = smem + 1024;              // [1024,2048)
        float4* sboxS  = (float4*)(smem + 2048);   // [2048,4096)
        ull (*mrow)[2] = (ull (*)[2])(smem + 4096);// [4096,4352)
        float4* sOwn   = (float4*)(smem + 4352);   // [4352,4552)
        ull* sPreW     = smem + 4552;              // [4552,4554)

        for (int blk = blockIdx.x; blk < NBATCH * NFG; blk += GRID) {
            const int n = min(cntPad[blk * CPAD], CCAP);
            if (n == 0) {                          // uniform branch per block
                for (int i = t; i < NDET; i += TPB) svKeys[(size_t)blk * NDET + i] = 0ULL;
                continue;
            }
            const ull* srcK = cKeys + (size_t)blk * CCAP;
            const float4* srcB = cBox + (size_t)blk * CCAP;
            for (int i = t; i < n; i += TPB) sk[i] = srcK[i];
            __syncthreads();

            // rank-by-counting sort (desc), 1 key/thread; unique keys -> bijective
            {
                const ull myk = (t < n) ? sk[t] : 0ULL;
                const float4 myb = (t < n) ? srcB[t] : make_float4(0.f, 0.f, 0.f, 0.f);
                int rnk = 0;
                for (int j = 0; j < n; ++j) rnk += (sk[j] > myk) ? 1 : 0;
                __syncthreads();
                if (t < n) { sks[rnk] = myk; sboxS[rnk] = myb; }
            }
            if (t == 0) s_ns = 0;
            __syncthreads();

            // chunked suppression-matrix greedy NMS (R14-validated)
            int nsTot = 0;
            for (int cb = 0; cb < n && nsTot < NDET; cb += CHUNK) {
                const int C = min(CHUNK, n - cb);
                bool pre = false;
                if (t < C) {
                    const float4 Q = sboxS[cb + t];
                    const float aq = (Q.z - Q.x) * (Q.w - Q.y);
                    for (int l = 0; l < nsTot; ++l)
                        if (iou_gt(sOwn[l], Q, aq)) { pre = true; break; }
                }
                const ull bal = __ballot(pre);
                if (t == 0)  sPreW[0] = bal;       // chunk idx 0..63
                if (t == 64) sPreW[1] = bal;       // chunk idx 64..127
                if (t < 256) {
                    const int r = t >> 1, w = t & 1;
                    ull word = 0ULL;
                    if (r < C) {
                        const float4 R = sboxS[cb + r];
                        const int j0 = w * 64;
                        const int jend = min(j0 + 64, C);
                        for (int j = (j0 > r + 1 ? j0 : r + 1); j < jend; ++j) {
                            const float4 Q = sboxS[cb + j];
                            const float aq = (Q.z - Q.x) * (Q.w - Q.y);
                            if (iou_gt(R, Q, aq)) word |= (1ULL << (j - j0));
                        }
                    }
                    mrow[r][w] = word;
                }
                __syncthreads();
                if (t == 0) {
                    ull S0 = sPreW[0], S1 = sPreW[1];
                    int ns = nsTot;
                    ull r0 = mrow[0][0], r1 = mrow[0][1];
                    for (int i = 0; i < C && ns < NDET; ++i) {
                        const ull nr0 = (i + 1 < C) ? mrow[i + 1][0] : 0ULL;
                        const ull nr1 = (i + 1 < C) ? mrow[i + 1][1] : 0ULL;
                        const bool dead = (i < 64) ? ((S0 >> i) & 1ULL)
                                                   : ((S1 >> (i - 64)) & 1ULL);
                        if (!dead) {
                            sOwn[ns] = sboxS[cb + i];
                            svKeys[(size_t)blk * NDET + ns] = sks[cb + i];
                            ++ns;
                            S0 |= r0; S1 |= r1;
                        }
                        r0 = nr0; r1 = nr1;
                    }
                    s_ns = ns;
                }
                __syncthreads();
                nsTot = s_ns;
            }
            for (int i = nsTot + t; i < NDET; i += TPB) svKeys[(size_t)blk * NDET + i] = 0ULL;
            __syncthreads();                       // smem safe for next blk iter
        }
    }
    grid.sync();

    // ---------------- Phase 3: radix top-100 select (blocks 0..3) -------------
    if (blockIdx.x >= NBATCH) return;
    {
        const int b = blockIdx.x;
        ull* F      = smem;                        // [0,2048) fast-path keys
        int* hist   = (int*)(smem + 2048);         // 4096 ints
        ull* chosen = smem + 4096;                 // [4096,4196)
        ull* wred   = smem + 4196;                 // [4196,4212)

        if (t == 0) { s_T = -1; s_above = 0; s_total = 0; }
        #pragma unroll
        for (int j = 0; j < 4; ++j) hist[t + j * 1024] = 0;
        for (int i = t; i < NDET; i += TPB) chosen[i] = 0ULL;

        const ull* src = svKeys + (size_t)b * SLOTS;
        ull keys[9];
        #pragma unroll
        for (int j = 0; j < 9; ++j) {
            const int s = t + j * 1024;
            keys[j] = (s < SLOTS) ? src[s] : 0ULL;
        }
        __syncthreads();

        #pragma unroll
        for (int j = 0; j < 9; ++j) {
            if (keys[j] != 0ULL) atomicAdd(&hist[(unsigned)(keys[j] >> 52)], 1);
        }
        __syncthreads();

        {
            const int gbase = (1023 - t) * 4;      // thread 0 owns highest buckets
            const int s0 = hist[gbase] + hist[gbase + 1] + hist[gbase + 2] + hist[gbase + 3];
            const int pre = block_excl_scan(s0, t, wtot);
            int acc = pre;
            for (int d = gbase + 3; d >= gbase; --d) {
                const int h = hist[d];
                if (acc < NDET && acc + h >= NDET) { s_T = d; s_above = acc; } // unique
                acc += h;
            }
            if (t == 1023) s_total = acc;
        }
        __syncthreads();

        const int T = s_T, total = s_total;
        const int n2 = (T < 0) ? total : (s_above + hist[T]);

        if (n2 <= 2048) {
            // deterministic compaction of {digit >= T} (superset of top-100)
            int mycnt = 0;
            #pragma unroll
            for (int j = 0; j < 9; ++j) {
                const ull k = keys[j];
                if (k && (T < 0 || (int)(k >> 52) >= T)) ++mycnt;
            }
            int off = block_excl_scan(mycnt, t, wtot);
            #pragma unroll
            for (int j = 0; j < 9; ++j) {
                const ull k = keys[j];
                if (k && (T < 0 || (int)(k >> 52) >= T)) F[off++] = k;
            }
            __syncthreads();
            // rank-sort (2 keys/thread); unique keys -> bijective ranks
            ull myk0 = (t < n2) ? F[t] : 0ULL;
            ull myk1 = (t + 1024 < n2) ? F[t + 1024] : 0ULL;
            int r0 = 0, r1 = 0;
            for (int j = 0; j < n2; ++j) {
                const ull kj = F[j];
                r0 += (kj > myk0) ? 1 : 0;
                r1 += (kj > myk1) ? 1 : 0;
            }
            __syncthreads();
            if (t < n2 && r0 < NDET) chosen[r0] = myk0;
            if (t + 1024 < n2 && r1 < NDET) chosen[r1] = myk1;
            __syncthreads();
        } else {
            // guaranteed-correct fallback (unreachable for real score data):
            // 100 bounded-argmax rounds, strictly descending upper bound.
            ull ub = ~0ULL;
            for (int r = 0; r < NDET; ++r) {
                ull best = 0ULL;
                #pragma unroll
                for (int j = 0; j < 9; ++j) {
                    const ull k = keys[j];
                    if (k < ub && k > best) best = k;
                }
                #pragma unroll
                for (int o = 32; o > 0; o >>= 1) {
                    const ull ob = __shfl_down(best, o);
                    if (ob > best) best = ob;
                }
                if (lane == 0) wred[wid] = best;
                __syncthreads();
                if (t == 0) {
                    ull mx = wred[0];
                    for (int w2 = 1; w2 < 16; ++w2) if (wred[w2] > mx) mx = wred[w2];
                    s_best = mx;
                    if (mx) chosen[r] = mx;
                }
                __syncthreads();
                if (s_best == 0ULL) break;
                ub = s_best;
                __syncthreads();
            }
        }

        // decode outputs (validated epilogue)
        float* oB = out + (size_t)b * NDET * 4;
        float* oS = out + (size_t)NBATCH * NDET * 4 + (size_t)b * NDET;
        float* oL = out + (size_t)NBATCH * NDET * 5 + (size_t)b * NDET;
        if (t < NDET) {
            const ull key = chosen[t];
            if (key != 0ULL) {
                const unsigned flat = ~(unsigned)key;
                const float score = __uint_as_float((unsigned)(key >> 32));
                const int np = flat / NFG;
                const int c  = (int)(flat - (unsigned)np * NFG) + 1;
                const float W = (float)imgsh[b * 2 + 1];
                const float H = (float)imgsh[b * 2 + 0];
                float bx1, by1, bx2, by2;
                decode_box(b, np, c, props, deltas, W, H, bx1, by1, bx2, by2);
                oB[t * 4 + 0] = bx1; oB[t * 4 + 1] = by1;
                oB[t * 4 + 2] = bx2; oB[t * 4 + 3] = by2;
                oS[t] = score;
                oL[t] = (float)c;
            } else {
                oB[t * 4 + 0] = 0.0f; oB[t * 4 + 1] = 0.0f;
                oB[t * 4 + 2] = 0.0f; oB[t * 4 + 3] = 0.0f;
                oS[t] = 0.0f; oL[t] = -1.0f;
            }
        }
    }
}

extern "C" void kernel_launch(void* const* d_in, const int* in_sizes, int n_in,
                              void* d_out, int out_size, void* d_ws, size_t ws_size,
                              hipStream_t stream)
{
    const float* logits = (const float*)d_in[0];   // [B*N, 91]
    const float* props  = (const float*)d_in[2];   // [B, N, 4]
    const float* deltas = (const float*)d_in[1];   // [B*N, 364]
    const int*   imgsh  = (const int*)d_in[3];     // [B, 2]
    float* out = (float*)d_out;

    char* w = (char*)d_ws;
    int* cntPad = (int*)w;
    w += (size_t)(NBATCH * NFG * CPAD) * sizeof(int);                              // 46 KB
    ull* svKeys = (ull*)w;
    w += (size_t)NBATCH * SLOTS * sizeof(ull);                                     // 288 KB
    ull* cKeys = (ull*)w;
    w += (size_t)NBATCH * NFG * CCAP * sizeof(ull);                                // 2.95 MB
    float4* cBox = (float4*)w;
    w += (size_t)NBATCH * NFG * CCAP * sizeof(float4);                             // 5.9 MB

    void* args[] = { (void*)&logits, (void*)&props, (void*)&deltas, (void*)&imgsh,
                     (void*)&cntPad, (void*)&cKeys, (void*)&cBox,
                     (void*)&svKeys, (void*)&out };
    hipLaunchCooperativeKernel((const void*)mega_kernel, dim3(GRID), dim3(TPB),
                               args, 0, stream);
}

// Round 23
// 74.720 us; speedup vs baseline: 2.2510x; 2.2510x over previous
//
#include <hip/hip_runtime.h>
#include <math.h>
#include <float.h>
#include <limits.h>

#define NBATCH 4
#define NPROP  4096
#define NCLS   91
#define NFG    90
#define NDET   100
#define CCAP   1024            // per-(image,class) candidate cap (avg ~80; never hit)
#define BN     (NBATCH * NPROP)
#define SLOTS  (NFG * NDET)    // 9000 survivor slots per image
#define FCAP   16384           // fallback sort capacity (pow2 >= SLOTS)
#define CHUNK  128             // NMS matrix-walk chunk size
#define NWORD  128             // 4096 proposals / 32 bits

static __device__ __forceinline__ float clampf(float x, float lo, float hi) {
    return fminf(fmaxf(x, lo), hi);
}

// Decode + clip one (proposal, class) box. Identical arithmetic everywhere it is
// used -> bitwise-identical results (validated absmax 0.0, R1-R22).
static __device__ __forceinline__ void decode_box(int b, int np, int c,
    const float* __restrict__ props, const float* __restrict__ deltas,
    float W, float H, float& bx1, float& by1, float& bx2, float& by2)
{
    const float* pr = props + ((size_t)b * NPROP + np) * 4;
    const float x1 = pr[0], y1 = pr[1], x2 = pr[2], y2 = pr[3];
    const float w = x2 - x1, h = y2 - y1;
    const float cx = x1 + 0.5f * w, cy = y1 + 0.5f * h;
    const float* d = deltas + (((size_t)b * NPROP + np) * NCLS + c) * 4;
    const float BBC = 4.135166556742356f;   // log(1000/16)
    const float dx = d[0] / 10.0f;
    const float dy = d[1] / 10.0f;
    const float dw = fminf(d[2] / 5.0f, BBC);
    const float dh = fminf(d[3] / 5.0f, BBC);
    const float pcx = dx * w + cx;
    const float pcy = dy * h + cy;
    const float pw = expf(dw) * w;
    const float ph = expf(dh) * h;
    bx1 = clampf(pcx - 0.5f * pw, 0.0f, W);
    by1 = clampf(pcy - 0.5f * ph, 0.0f, H);
    bx2 = clampf(pcx + 0.5f * pw, 0.0f, W);
    by2 = clampf(pcy + 0.5f * ph, 0.0f, H);
}

// IoU > 0.5 predicate, identical float expression to all validated rounds.
static __device__ __forceinline__ bool iou_gt(const float4 S, const float4 Q, float aq)
{
    const float iw = fmaxf(fminf(S.z, Q.z) - fmaxf(S.x, Q.x), 0.0f);
    const float ih = fmaxf(fminf(S.w, Q.w) - fmaxf(S.y, Q.y), 0.0f);
    const float inter = iw * ih;
    const float as = (S.z - S.x) * (S.w - S.y);
    return inter / (as + aq - inter) > 0.5f;
}

// Block-wide exclusive scan over 1024 threads (wave shfl scan + wave totals).
static __device__ __forceinline__ int block_excl_scan(int v, int t, int* wtot)
{
    const int lane = t & 63, wid = t >> 6;
    int inc = v;
    #pragma unroll
    for (int s = 1; s < 64; s <<= 1) {
        const int u = __shfl_up(inc, s);
        if (lane >= s) inc += u;
    }
    if (lane == 63) wtot[wid] = inc;
    __syncthreads();
    int base = 0;
    for (int w2 = 0; w2 < wid; ++w2) base += wtot[w2];
    __syncthreads();                 // protect wtot for the next call
    return base + inc - v;
}

// Kernel 1: per-proposal softmax stats + 91-bit FINAL candidate mask.
// UNCHANGED from validated R9-R17.
__global__ __launch_bounds__(256) void stats_mask_kernel(
    const float* __restrict__ logits, const float* __restrict__ props,
    const float* __restrict__ deltas, const int* __restrict__ imgsh,
    float2* __restrict__ stats, unsigned* __restrict__ mask)
{
    const int wavei = threadIdx.x >> 6;
    const int lane  = threadIdx.x & 63;
    const int p = blockIdx.x * 4 + wavei;          // 0 .. B*N-1
    const int b = p >> 12;
    const int np = p & (NPROP - 1);
    const float* lrow = logits + (size_t)p * NCLS;

    const float a  = lrow[lane];
    const float a2 = (lane + 64 < NCLS) ? lrow[lane + 64] : -INFINITY;

    float m = fmaxf(a, a2);                        // level s=64
    #pragma unroll
    for (int s = 32; s > 0; s >>= 1) m = fmaxf(m, __shfl_down(m, s));
    m = __shfl(m, 0);

    const float e0 = expf(a - m);
    const float e1 = (lane + 64 < NCLS) ? expf(a2 - m) : 0.0f;
    float sum = e0 + e1;                           // level s=64
    #pragma unroll
    for (int s = 32; s > 0; s >>= 1) sum += __shfl_down(sum, s);
    sum = __shfl(sum, 0);

    const float W = (float)imgsh[b * 2 + 1];
    const float H = (float)imgsh[b * 2 + 0];

    bool pass0 = ((e0 / sum) > 0.05f) && (lane >= 1);     // class = lane (skip bg 0)
    if (pass0) {
        float bx1, by1, bx2, by2;
        decode_box(b, np, lane, props, deltas, W, H, bx1, by1, bx2, by2);
        pass0 = ((bx2 - bx1) >= 0.01f) && ((by2 - by1) >= 0.01f);
    }
    bool pass1 = ((e1 / sum) > 0.05f);                    // class = lane+64 (<= 90)
    if (pass1) {
        float bx1, by1, bx2, by2;
        decode_box(b, np, lane + 64, props, deltas, W, H, bx1, by1, bx2, by2);
        pass1 = ((bx2 - bx1) >= 0.01f) && ((by2 - by1) >= 0.01f);
    }

    const unsigned long long b0 = __ballot(pass0);        // classes 0..63
    const unsigned long long b1 = __ballot(pass1);        // classes 64..90

    if (lane == 0) {
        stats[p] = make_float2(m, sum);
        mask[p]          = (unsigned)b0;           // plane 0: classes  0..31
        mask[BN + p]     = (unsigned)(b0 >> 32);   // plane 1: classes 32..63
        mask[2 * BN + p] = (unsigned)b1;           // plane 2: classes 64..90
    }
}

// Kernel 2: parallel bit-transpose: mask planes [3][BN] -> maskT[b][c][128
// words]. 64 blocks x 256 thr, LDS only, NO atomics, fully deterministic.
__global__ __launch_bounds__(256) void maskt_kernel(
    const unsigned* __restrict__ mask, unsigned* __restrict__ maskT)
{
    const int blk = blockIdx.x;                    // 0..63
    const int b = blk >> 4;                        // image
    const int s = blk & 15;                        // slice of 256 proposals
    const int t = threadIdx.x;
    __shared__ unsigned lm[3 * 256];               // 3 KB

    #pragma unroll
    for (int j = 0; j < 3; ++j)
        lm[j * 256 + t] = mask[(size_t)j * BN + b * NPROP + s * 256 + t];
    __syncthreads();

    for (int idx = t; idx < NCLS * 8; idx += 256) {   // (class, word-in-slice)
        const int c = idx >> 3, w = idx & 7;
        const int plane = c >> 5, bitpos = c & 31;
        const unsigned* src = &lm[plane * 256 + w * 32];
        unsigned word = 0;
        #pragma unroll
        for (int k = 0; k < 32; ++k)
            word |= ((src[k] >> bitpos) & 1u) << k;
        maskT[((size_t)(b * NCLS + c)) * NWORD + s * 8 + w] = word;
    }
}

// Kernel 3: one block (256 threads) per (image, class). Gather = 512 B column
// read + popcount-scan enumeration (deterministic, no atomics) -> rank-sort
// (R15-validated) -> decode -> chunked suppression-matrix NMS (R14-validated).
__global__ __launch_bounds__(256) void class_nms_kernel(
    const float* __restrict__ logits, const float2* __restrict__ stats,
    const unsigned* __restrict__ maskT,
    const float* __restrict__ props, const float* __restrict__ deltas,
    const int* __restrict__ imgsh, unsigned long long* __restrict__ svKeys)
{
    const int blk  = blockIdx.x;                   // 0..359
    const int b    = blk / NFG;
    const int cm1  = blk % NFG;                    // class - 1
    const int c    = cm1 + 1;
    const int t    = threadIdx.x;
    const int lane = t & 63;

    __shared__ unsigned wbuf[NWORD];               // 512 B mask column
    __shared__ int wt2[2];
    __shared__ unsigned long long sk[CCAP];        // 8 KB, gathered (np order)
    __shared__ unsigned long long sks[CCAP];       // 8 KB, sorted desc
    __shared__ float4 sbox[CCAP];                  // 16 KB (boxes of sorted keys)
    __shared__ unsigned long long mrow[CHUNK][2];  // 2 KB suppression matrix
    __shared__ float4 sOwn[NDET];                  // accepted survivor boxes
    __shared__ unsigned long long sPreW[2];
    __shared__ int s_ns;

    const unsigned* col = maskT + ((size_t)(b * NCLS + c)) * NWORD;
    if (t < NWORD) wbuf[t] = col[t];
    __syncthreads();

    // popcount + exclusive scan over 128 words (2 waves) -> per-word offsets
    const int pc = (t < NWORD) ? __popc(wbuf[t]) : 0;
    int inc = pc;
    #pragma unroll
    for (int s = 1; s < 64; s <<= 1) {
        const int u = __shfl_up(inc, s);
        if (lane >= s) inc += u;
    }
    if (lane == 63 && (t >> 6) < 2) wt2[t >> 6] = inc;
    __syncthreads();
    const int ntot = wt2[0] + wt2[1];
    const int n = min(ntot, CCAP);
    if (n == 0) {
        for (int i = t; i < NDET; i += 256) svKeys[(size_t)blk * NDET + i] = 0ULL;
        return;
    }
    const int myoff = ((t >> 6) == 1 ? wt2[0] : 0) + inc - pc;

    // enumerate hits (deterministic positions, ascending np within word order)
    if (t < NWORD) {
        unsigned wv = wbuf[t];
        int o = myoff;
        while (wv) {
            const int k = __ffs(wv) - 1; wv &= wv - 1;
            const int np = t * 32 + k;
            const int p = b * NPROP + np;
            const float lg = logits[(size_t)p * NCLS + c];
            const float2 st = stats[p];
            const float score = expf(lg - st.x) / st.y;   // bitwise = kernel-1 value
            const unsigned flat = (unsigned)(np * NFG + cm1);
            const unsigned long long key =
                ((unsigned long long)__float_as_uint(score) << 32) | (unsigned)(~flat);
            if (o < CCAP) sk[o] = key;
            ++o;
        }
    }
    __syncthreads();

    // ---- rank-by-counting sort (descending); unique keys -> bijective ranks ----
    {
        unsigned long long myk[4];
        int rnk[4] = {0, 0, 0, 0};
        #pragma unroll
        for (int e = 0; e < 4; ++e)
            myk[e] = (t + e * 256 < n) ? sk[t + e * 256] : 0ULL;
        #pragma unroll 4
        for (int j = 0; j < n; ++j) {
            const unsigned long long kj = sk[j];
            #pragma unroll
            for (int e = 0; e < 4; ++e) rnk[e] += (kj > myk[e]) ? 1 : 0;
        }
        #pragma unroll
        for (int e = 0; e < 4; ++e)
            if (t + e * 256 < n) sks[rnk[e]] = myk[e];
    }
    __syncthreads();

    // ---- decode boxes ONCE for sorted candidates ----
    const float W = (float)imgsh[b * 2 + 1];
    const float H = (float)imgsh[b * 2 + 0];
    for (int i = t; i < n; i += 256) {
        const unsigned flat = ~(unsigned)sks[i];
        const int np = flat / NFG;                 // flat % NFG == cm1 by construction
        float bx1, by1, bx2, by2;
        decode_box(b, np, c, props, deltas, W, H, bx1, by1, bx2, by2);
        sbox[i] = make_float4(bx1, by1, bx2, by2);
    }
    if (t == 0) s_ns = 0;
    __syncthreads();

    // ---- chunked suppression-matrix greedy NMS (R14/R15-validated) ----
    int nsTot = 0;
    for (int cb = 0; cb < n && nsTot < NDET; cb += CHUNK) {
        const int C = min(CHUNK, n - cb);

        // (a) pre-suppression vs accepted survivors (free on chunk 1: nsTot==0)
        bool pre = false;
        if (t < C) {
            const float4 Q = sbox[cb + t];
            const float aq = (Q.z - Q.x) * (Q.w - Q.y);
            for (int l = 0; l < nsTot; ++l) {
                if (iou_gt(sOwn[l], Q, aq)) { pre = true; break; }
            }
        }
        const unsigned long long bal = __ballot(pre);
        if (t == 0)  sPreW[0] = bal;               // chunk idx 0..63
        if (t == 64) sPreW[1] = bal;               // chunk idx 64..127

        // (b) in-chunk suppression matrix: thread t -> row r = t>>1, word w = t&1
        {
            const int r = t >> 1, w = t & 1;
            unsigned long long word = 0ULL;
            if (r < C) {
                const float4 R = sbox[cb + r];     // row box (the earlier/suppressor)
                const int j0 = w * 64;
                const int jend = min(j0 + 64, C);
                for (int j = (j0 > r + 1 ? j0 : r + 1); j < jend; ++j) {
                    const float4 Q = sbox[cb + j];
                    const float aq = (Q.z - Q.x) * (Q.w - Q.y);
                    if (iou_gt(R, Q, aq)) word |= (1ULL << (j - j0));
                }
            }
            mrow[r][w] = word;
        }
        __syncthreads();

        // (c) scalar bitmask walk (thread 0): prefetched rows
        if (t == 0) {
            unsigned long long S0 = sPreW[0], S1 = sPreW[1];
            int ns = nsTot;
            unsigned long long r0 = mrow[0][0], r1 = mrow[0][1];
            for (int i = 0; i < C && ns < NDET; ++i) {
                const unsigned long long nr0 = (i + 1 < C) ? mrow[i + 1][0] : 0ULL;
                const unsigned long long nr1 = (i + 1 < C) ? mrow[i + 1][1] : 0ULL;
                const bool dead = (i < 64) ? ((S0 >> i) & 1ULL)
                                           : ((S1 >> (i - 64)) & 1ULL);
                if (!dead) {
                    sOwn[ns] = sbox[cb + i];
                    svKeys[(size_t)blk * NDET + ns] = sks[cb + i];
                    ++ns;
                    S0 |= r0; S1 |= r1;
                }
                r0 = nr0; r1 = nr1;
            }
            s_ns = ns;
        }
        __syncthreads();
        nsTot = s_ns;
    }

    // zero-fill unused survivor slots (deterministic)
    for (int i = nsTot + t; i < NDET; i += 256) svKeys[(size_t)blk * NDET + i] = 0ULL;
}

// Kernel 4: radix-select top-100. UNCHANGED from validated R12-R17.
__global__ __launch_bounds__(1024) void select_kernel(
    const unsigned long long* __restrict__ svKeys,
    const float* __restrict__ props, const float* __restrict__ deltas,
    const int* __restrict__ imgsh, float* __restrict__ out)
{
    const int b = blockIdx.x;
    const int t = threadIdx.x;
    __shared__ unsigned long long F[FCAP];         // 128 KB (sort buffer)
    __shared__ int hist[4096];                     // 16 KB
    __shared__ int wtot[16];
    __shared__ int s_T, s_above, s_total;

    if (t == 0) { s_T = -1; s_above = 0; s_total = 0; }
    #pragma unroll
    for (int j = 0; j < 4; ++j) hist[t + j * 1024] = 0;

    const unsigned long long* src = svKeys + (size_t)b * SLOTS;
    unsigned long long keys[9];
    #pragma unroll
    for (int j = 0; j < 9; ++j) {
        const int s = t + j * 1024;
        keys[j] = (s < SLOTS) ? src[s] : 0ULL;
    }
    __syncthreads();

    #pragma unroll
    for (int j = 0; j < 9; ++j) {
        if (keys[j] != 0ULL) atomicAdd(&hist[(unsigned)(keys[j] >> 52)], 1);
    }
    __syncthreads();

    {
        const int gbase = (1023 - t) * 4;
        const int s0 = hist[gbase] + hist[gbase + 1] + hist[gbase + 2] + hist[gbase + 3];
        const int pre = block_excl_scan(s0, t, wtot);   // counts in all higher buckets
        int acc = pre;
        for (int d = gbase + 3; d >= gbase; --d) {
            const int h = hist[d];
            if (acc < NDET && acc + h >= NDET) { s_T = d; s_above = acc; }  // unique
            acc += h;
        }
        if (t == 1023) s_total = acc;              // lowest group finishes the total
    }
    __syncthreads();

    const int T = s_T;
    const int total = s_total;
    const int n2 = (T < 0) ? total : (s_above + hist[T]);
    const bool fast = (n2 <= 2048);

    int mycnt = 0;
    #pragma unroll
    for (int j = 0; j < 9; ++j) {
        const unsigned long long k = keys[j];
        const bool m = (k != 0ULL) && (fast ? (T < 0 || (int)(k >> 52) >= T) : true);
        mycnt += m ? 1 : 0;
    }
    int off = block_excl_scan(mycnt, t, wtot);
    #pragma unroll
    for (int j = 0; j < 9; ++j) {
        const unsigned long long k = keys[j];
        const bool m = (k != 0ULL) && (fast ? (T < 0 || (int)(k >> 52) >= T) : true);
        if (m) F[off++] = k;
    }
    const int nsort = fast ? n2 : total;

    int P = 128; while (P < nsort) P <<= 1;        // pow2 pad, >= 128, <= FCAP
    for (int i = nsort + t; i < P; i += 1024) F[i] = 0ULL;

    for (unsigned kk = 2; kk <= (unsigned)P; kk <<= 1) {
        for (unsigned jj = kk >> 1; jj > 0; jj >>= 1) {
            __syncthreads();
            for (unsigned i = t; i < (unsigned)P; i += 1024) {
                const unsigned ixj = i ^ jj;
                if (ixj > i) {
                    const unsigned long long x = F[i], y = F[ixj];
                    const bool up = ((i & kk) == 0);       // descending when up
                    if (up ? (x < y) : (x > y)) { F[i] = y; F[ixj] = x; }
                }
            }
        }
    }
    __syncthreads();

    float* oB = out + (size_t)b * NDET * 4;
    float* oS = out + (size_t)NBATCH * NDET * 4 + (size_t)b * NDET;
    float* oL = out + (size_t)NBATCH * NDET * 5 + (size_t)b * NDET;
    if (t < NDET) {
        const unsigned long long key = F[t];       // P >= 128 > NDET, zero-padded
        if (key != 0ULL) {
            const unsigned flat = ~(unsigned)key;
            const float score = __uint_as_float((unsigned)(key >> 32));
            const int np = flat / NFG;
            const int c  = (int)(flat - (unsigned)np * NFG) + 1;
            const float W = (float)imgsh[b * 2 + 1];
            const float H = (float)imgsh[b * 2 + 0];
            float bx1, by1, bx2, by2;
            decode_box(b, np, c, props, deltas, W, H, bx1, by1, bx2, by2);
            oB[t * 4 + 0] = bx1; oB[t * 4 + 1] = by1;
            oB[t * 4 + 2] = bx2; oB[t * 4 + 3] = by2;
            oS[t] = score;
            oL[t] = (float)c;
        } else {
            oB[t * 4 + 0] = 0.0f; oB[t * 4 + 1] = 0.0f;
            oB[t * 4 + 2] = 0.0f; oB[t * 4 + 3] = 0.0f;
            oS[t] = 0.0f; oL[t] = -1.0f;
        }
    }
}

extern "C" void kernel_launch(void* const* d_in, const int* in_sizes, int n_in,
                              void* d_out, int out_size, void* d_ws, size_t ws_size,
                              hipStream_t stream)
{
    const float* logits = (const float*)d_in[0];   // [B*N, 91]
    const float* deltas = (const float*)d_in[1];   // [B*N, 364]
    const float* props  = (const float*)d_in[2];   // [B, N, 4]
    const int*   imgsh  = (const int*)d_in[3];     // [B, 2]
    float* out = (float*)d_out;

    char* w = (char*)d_ws;
    float2* stats = (float2*)w;            w += (size_t)BN * sizeof(float2);       // 128 KB
    unsigned* mask = (unsigned*)w;         w += (size_t)3 * BN * sizeof(unsigned); // 192 KB
    unsigned long long* svKeys = (unsigned long long*)w;
    w += (size_t)NBATCH * SLOTS * sizeof(unsigned long long);                      // 288 KB
    unsigned* maskT = (unsigned*)w;
    w += (size_t)NBATCH * NCLS * NWORD * sizeof(unsigned);                         // 186 KB

    stats_mask_kernel<<<BN / 4, 256, 0, stream>>>(logits, props, deltas, imgsh, stats, mask);
    maskt_kernel<<<NBATCH * 16, 256, 0, stream>>>(mask, maskT);
    class_nms_kernel<<<NBATCH * NFG, 256, 0, stream>>>(
        logits, stats, maskT, props, deltas, imgsh, svKeys);
    select_kernel<<<NBATCH, 1024, 0, stream>>>(svKeys, props, deltas, imgsh, out);
}